// Round 2
// baseline (456.340 us; speedup 1.0000x reference)
//
#include <hip/hip_runtime.h>

typedef __bf16 bf16x8 __attribute__((ext_vector_type(8)));
typedef float f32x4 __attribute__((ext_vector_type(4)));

#define MFMA16(a, b, c) __builtin_amdgcn_mfma_f32_16x16x32_bf16(a, b, c, 0, 0, 0)
#define LOG2E 1.44269504088896340736f

__device__ __forceinline__ unsigned short f2bf(float f) {
  union { float f; unsigned u; } v; v.f = f;
  return (unsigned short)((v.u + 0x7fffu + ((v.u >> 16) & 1u)) >> 16);
}
__device__ __forceinline__ bf16x8 ld_frag(const unsigned short* p) {
  return *(const bf16x8*)p;  // 16B-aligned by construction
}
__device__ __forceinline__ void gld_lds16(const unsigned short* g, unsigned short* l) {
  __builtin_amdgcn_global_load_lds(
      (const __attribute__((address_space(1))) unsigned int*)(const void*)g,
      (__attribute__((address_space(3))) unsigned int*)(void*)l, 16, 0, 0);
}

// fp32 -> bf16, 4 elements/thread
__global__ void cvt_f2bf(const float* __restrict__ in,
                         unsigned short* __restrict__ out, int n4) {
  int i = blockIdx.x * blockDim.x + threadIdx.x;
  if (i < n4) {
    float4 v = ((const float4*)in)[i];
    ushort4 o;
    o.x = f2bf(v.x); o.y = f2bf(v.y); o.z = f2bf(v.z); o.w = f2bf(v.w);
    ((ushort4*)out)[i] = o;
  }
}

// ---------------------------------------------------------------------------
// C[M,N] = A[M,K] * B[N,K]^T + bias[N]   (A,B bf16; bias fp32)
// mode 0: store fp32 to outf[M,N]
// mode 1: QKV split: n<512 -> qbuf; n<1024 -> kbuf; else transposed vtbuf[b][d][s]
// 128x128 tile, BK=32, 256 threads, 4 waves in 2x2, wave tile 64x64.
// ---------------------------------------------------------------------------
__global__ void gemm_bt(const unsigned short* __restrict__ A,
                        const unsigned short* __restrict__ B,
                        const float* __restrict__ bias,
                        float* __restrict__ outf,
                        unsigned short* __restrict__ qbuf,
                        unsigned short* __restrict__ kbuf,
                        unsigned short* __restrict__ vtbuf,
                        int M, int N, int K, int mode) {
  __shared__ alignas(16) unsigned short As[128 * 32];
  __shared__ alignas(16) unsigned short Bs[128 * 32];
  const int n0 = blockIdx.x * 128, m0 = blockIdx.y * 128;
  const int tid = threadIdx.x;
  const int l = tid & 63, w = tid >> 6;
  const int quad = l >> 4, c = l & 15;
  const int wm = (w >> 1) * 64, wn = (w & 1) * 64;

  f32x4 acc[4][4] = {};
  const int kiters = K >> 5;
  for (int kt = 0; kt < kiters; ++kt) {
    __syncthreads();
    const int kk = kt * 32 + (l & 3) * 8;
    const int row = l >> 2;
#pragma unroll
    for (int i = 0; i < 2; ++i) {
      const int rbase = i * 64 + w * 16;
      gld_lds16(&A[(size_t)(m0 + rbase + row) * K + kk], &As[rbase * 32]);
      gld_lds16(&B[(size_t)(n0 + rbase + row) * K + kk], &Bs[rbase * 32]);
    }
    __syncthreads();
    bf16x8 af[4], bfr[4];
#pragma unroll
    for (int t = 0; t < 4; ++t) {
      af[t] = ld_frag(&As[(wm + t * 16 + c) * 32 + quad * 8]);
      bfr[t] = ld_frag(&Bs[(wn + t * 16 + c) * 32 + quad * 8]);
    }
#pragma unroll
    for (int mt = 0; mt < 4; ++mt)
#pragma unroll
      for (int nt = 0; nt < 4; ++nt)
        acc[mt][nt] = MFMA16(af[mt], bfr[nt], acc[mt][nt]);
  }

#pragma unroll
  for (int nt = 0; nt < 4; ++nt) {
    const int n = n0 + wn + nt * 16 + c;
    const float bsum = bias[n];
#pragma unroll
    for (int mt = 0; mt < 4; ++mt) {
      const int mbase = m0 + wm + mt * 16 + quad * 4;
      if (mode == 0) {
#pragma unroll
        for (int r = 0; r < 4; ++r)
          outf[(size_t)(mbase + r) * N + n] = acc[mt][nt][r] + bsum;
      } else if (n < 1024) {
        unsigned short* dst = (n < 512) ? qbuf : kbuf;
        const int nn = n & 511;
#pragma unroll
        for (int r = 0; r < 4; ++r)
          dst[(size_t)(mbase + r) * 512 + nn] = f2bf(acc[mt][nt][r] + bsum);
      } else {
        const int d = n - 1024;
        const int bb = mbase >> 12, s = mbase & 4095;
        ushort4 pk;
        pk.x = f2bf(acc[mt][nt][0] + bsum);
        pk.y = f2bf(acc[mt][nt][1] + bsum);
        pk.z = f2bf(acc[mt][nt][2] + bsum);
        pk.w = f2bf(acc[mt][nt][3] + bsum);
        *(ushort4*)&vtbuf[((size_t)bb * 512 + d) * 4096 + s] = pk;
      }
    }
  }
}

// ---------------------------------------------------------------------------
// Flash attention, transposed-S, kv-split-2, d-split PV, V-direct:
// Grid 512 = 4b x 64qt x 2 kv-halves; block owns 64 q x 2048 kv (64 iters).
// QK^T: q-split (wave w owns q = w*16+c, Q pinned in regs, K from dbuf LDS).
// PV: d-split (wave w owns d in [128w,128w+128) for ALL 64 q); V^T fragments
// read DIRECTLY from global (d-split gives V zero cross-wave reuse -> LDS
// staging was pure overhead). Raw s_barrier + per-wave waitcnt discipline:
//   A: vmcnt(0)+barrier  (K(it) staged+visible; p_lds(it-1) reads done)
//   B: lgkmcnt(0)+barrier (P(it) visible; K(it) reads done)
// K double-buffered; stage(it+1) issued right after A -> ~full iter of flight.
// Regs: o = 8x4 f32x4 = 128 AGPR, VGPR ~128 -> 2 blocks/CU (8 waves).
// ---------------------------------------------------------------------------
#define KROW 520
#define PROW 40
#define KBUF (32 * KROW)

__global__ __launch_bounds__(256, 2) void attn_kernel(
    const unsigned short* __restrict__ Q, const unsigned short* __restrict__ Kb,
    const unsigned short* __restrict__ Vt, unsigned short* __restrict__ part0,
    unsigned short* __restrict__ part1, float2* __restrict__ mlbuf) {
  __shared__ alignas(16) unsigned short k_lds[2 * KBUF];
  __shared__ alignas(16) unsigned short p_lds[64 * PROW];
  __shared__ float alpha_s[64];  // per-q rescale factor (and l at epilogue)
  __shared__ int flag_s[4];      // per-softmax-wave rescale flag

  const int bid = blockIdx.x;
  const int xcd = bid & 7;
  const int b = xcd >> 1;                          // 2 XCDs per batch
  const int half = (bid >> 3) & 1;                 // kv half
  const int qt = (bid >> 4) | ((xcd & 1) << 5);    // 0..63
  const int s0 = qt * 64;
  const int kvbase = half * 2048;
  const int tid = threadIdx.x;
  const int l = tid & 63, w = tid >> 6;
  const int quad = l >> 4, c = l & 15;
  const size_t boff = (size_t)b * 4096 * 512;

  const unsigned short* Kbase = Kb + boff;

  auto stage_k = [&](int kv0, int bufbase) {
#pragma unroll
    for (int i = 0; i < 8; ++i) {  // K: one 1KB row per wave per call
      const int row = i * 4 + w;
      gld_lds16(&Kbase[(size_t)(kv0 + row) * 512 + l * 8],
                &k_lds[bufbase + row * KROW]);
    }
  };

  stage_k(kvbase, 0);  // prologue: K(0) -> buf0

  // Q fragments pinned (A/B-operand layout: idx = c, k = quad*8+j)
  bf16x8 qf[16];
  {
    const unsigned short* qrow = Q + boff + (size_t)(s0 + w * 16 + c) * 512;
#pragma unroll
    for (int ks = 0; ks < 16; ++ks) qf[ks] = ld_frag(&qrow[ks * 32 + quad * 8]);
  }

  // O^T, d-split: o[t][j] holds [d = w*128 + t*16 + quad*4 + r][q = j*16 + c]
  f32x4 o[8][4] = {};
  float m_run = -1e30f, l_run = 0.f;  // per-lane (q = w*16+c), repl. over quads

  // per-lane V^T row pointer: d = w*128 + c (+ t*16 via imm-ish offsets)
  const unsigned short* vrow = Vt + (size_t)b * 512 * 4096 +
                               (size_t)(w * 128 + c) * 4096 + kvbase + quad * 8;

  for (int it = 0; it < 64; ++it) {
    const int cb = (it & 1) * KBUF;

    // --- A: own K-stage (issued last iter) complete, then block-wide sync.
    asm volatile("s_waitcnt vmcnt(0)" ::: "memory");
    __builtin_amdgcn_s_barrier();
    __builtin_amdgcn_sched_barrier(0);

    // stage K(it+1) into the other buffer: flies through this whole iter
    if (it + 1 < 64) stage_k(kvbase + (it + 1) * 32, KBUF - cb);

    // --- S^T = K Q^T (A = K frag, B = Q frag; identical lane layouts)
    f32x4 sa[2][2] = {};
    __builtin_amdgcn_s_setprio(1);
#pragma unroll
    for (int ks = 0; ks < 16; ++ks) {
      const unsigned short* kr = &k_lds[cb + c * KROW + ks * 32 + quad * 8];
      bf16x8 kf0 = ld_frag(kr);
      bf16x8 kf1 = ld_frag(kr + 16 * KROW);
      sa[0][ks & 1] = MFMA16(kf0, qf[ks], sa[0][ks & 1]);
      sa[1][ks & 1] = MFMA16(kf1, qf[ks], sa[1][ks & 1]);
    }
    __builtin_amdgcn_s_setprio(0);
    const f32x4 s0v = sa[0][0] + sa[0][1];  // kv = quad*4+r, q = w*16+c
    const f32x4 s1v = sa[1][0] + sa[1][1];  // kv = 16+quad*4+r

    // online softmax for own 16 q: 8 kv in-lane + 2 cross-quad shuffles
    const float C1 = 0.125f * LOG2E;
    float m8 = fmaxf(fmaxf(fmaxf(s0v[0], s0v[1]), fmaxf(s0v[2], s0v[3])),
                     fmaxf(fmaxf(s1v[0], s1v[1]), fmaxf(s1v[2], s1v[3])));
    m8 = fmaxf(m8, __shfl_xor(m8, 16));
    m8 = fmaxf(m8, __shfl_xor(m8, 32));

    // defer-max (T13): only rescale when the tile max grows > 8 raw units
    // (exp2 arg bounded by 8*C1 = 1.44 -> P <= 2.72, safe in fp32 accum)
    const bool need = __any(m8 - m_run > 8.0f);
    float alpha = 1.0f;
    if (need) {
      const float mn = fmaxf(m_run, m8);
      alpha = exp2f((m_run - mn) * C1);
      m_run = mn;
      l_run *= alpha;
    }

    float p0[4], p1[4], s8 = 0.f;
#pragma unroll
    for (int r = 0; r < 4; ++r) {
      p0[r] = exp2f((s0v[r] - m_run) * C1);
      p1[r] = exp2f((s1v[r] - m_run) * C1);
      s8 += p0[r] + p1[r];
    }
    // store P^T rows [q][kv] (two ushort4 = 2x ds_write_b64)
    unsigned short* prow = &p_lds[(w * 16 + c) * PROW];
    ushort4 pk0, pk1;
    pk0.x = f2bf(p0[0]); pk0.y = f2bf(p0[1]); pk0.z = f2bf(p0[2]); pk0.w = f2bf(p0[3]);
    pk1.x = f2bf(p1[0]); pk1.y = f2bf(p1[1]); pk1.z = f2bf(p1[2]); pk1.w = f2bf(p1[3]);
    *(ushort4*)&prow[quad * 4] = pk0;
    *(ushort4*)&prow[16 + quad * 4] = pk1;

    s8 += __shfl_xor(s8, 16);
    s8 += __shfl_xor(s8, 32);
    l_run += s8;

    if (quad == 0) alpha_s[w * 16 + c] = alpha;
    if (l == 0) flag_s[w] = need ? 1 : 0;

    // --- B: own P/alpha writes committed, then block-wide sync -> P visible.
    asm volatile("s_waitcnt lgkmcnt(0)" ::: "memory");
    __builtin_amdgcn_sched_barrier(0);
    __builtin_amdgcn_s_barrier();
    __builtin_amdgcn_sched_barrier(0);

    // per-q-group rescale of the d-split accumulator (uniform branch per group)
    const int f0 = flag_s[0], f1 = flag_s[1], f2 = flag_s[2], f3 = flag_s[3];
    if (f0) {
      const float a = alpha_s[c];
#pragma unroll
      for (int t = 0; t < 8; ++t) o[t][0] *= a;
    }
    if (f1) {
      const float a = alpha_s[16 + c];
#pragma unroll
      for (int t = 0; t < 8; ++t) o[t][1] *= a;
    }
    if (f2) {
      const float a = alpha_s[32 + c];
#pragma unroll
      for (int t = 0; t < 8; ++t) o[t][2] *= a;
    }
    if (f3) {
      const float a = alpha_s[48 + c];
#pragma unroll
      for (int t = 0; t < 8; ++t) o[t][3] *= a;
    }

    // --- O^T += V^T P^T, d-split: A = V frag DIRECT from global (L2),
    // B = P frag from LDS (reused over 8 d-tiles).
    const bf16x8 pf0 = ld_frag(&p_lds[(size_t)c * PROW + quad * 8]);
    const bf16x8 pf1 = ld_frag(&p_lds[(size_t)(16 + c) * PROW + quad * 8]);
    const bf16x8 pf2 = ld_frag(&p_lds[(size_t)(32 + c) * PROW + quad * 8]);
    const bf16x8 pf3 = ld_frag(&p_lds[(size_t)(48 + c) * PROW + quad * 8]);
    const unsigned short* vi = vrow + it * 32;
    __builtin_amdgcn_s_setprio(1);
#pragma unroll
    for (int t = 0; t < 8; ++t) {
      const bf16x8 vf = ld_frag(vi + (size_t)t * 16 * 4096);
      o[t][0] = MFMA16(vf, pf0, o[t][0]);
      o[t][1] = MFMA16(vf, pf1, o[t][1]);
      o[t][2] = MFMA16(vf, pf2, o[t][2]);
      o[t][3] = MFMA16(vf, pf3, o[t][3]);
    }
    __builtin_amdgcn_s_setprio(0);
  }

  // epilogue: exchange l across waves (softmax q-split -> O d-split), then
  // write normalized partial + (m,l) for the merge
  __syncthreads();  // all waves done reading alpha_s in their last rescale
  if (quad == 0) {
    alpha_s[w * 16 + c] = l_run;
    float2 ml; ml.x = m_run; ml.y = l_run;
    mlbuf[(size_t)half * 16384 + b * 4096 + s0 + w * 16 + c] = ml;
  }
  __syncthreads();
  const float linv0 = 1.0f / alpha_s[c];
  const float linv1 = 1.0f / alpha_s[16 + c];
  const float linv2 = 1.0f / alpha_s[32 + c];
  const float linv3 = 1.0f / alpha_s[48 + c];

  unsigned short* part = half ? part1 : part0;
  unsigned short* obase = part + boff + (size_t)s0 * 512 + w * 128 + quad * 4;
#pragma unroll
  for (int t = 0; t < 8; ++t) {
    const float li[4] = {linv0, linv1, linv2, linv3};
#pragma unroll
    for (int j = 0; j < 4; ++j) {
      ushort4 pk;
      pk.x = f2bf(o[t][j][0] * li[j]);
      pk.y = f2bf(o[t][j][1] * li[j]);
      pk.z = f2bf(o[t][j][2] * li[j]);
      pk.w = f2bf(o[t][j][3] * li[j]);
      *(ushort4*)&obase[(size_t)(j * 16 + c) * 512 + t * 16] = pk;
    }
  }
}

// ---------------------------------------------------------------------------
// Merge the two kv-half streams: out = (w0*P0 + w1*P1), w_h = l_h*2^((m_h-M)*C1)
// 8 elems/thread; writes in place over part0.
// ---------------------------------------------------------------------------
__global__ void merge_halves(const unsigned short* __restrict__ p1,
                             const float2* __restrict__ mlbuf,
                             unsigned short* __restrict__ p0out) {
  const int i = blockIdx.x * blockDim.x + threadIdx.x;  // one per 8 elems
  const int row = i >> 6;                               // 512 d / 8 = 64
  const float2 a = mlbuf[row];
  const float2 bb = mlbuf[16384 + row];
  const float C1 = 0.125f * LOG2E;
  const float M = fmaxf(a.x, bb.x);
  float w0 = a.y * exp2f((a.x - M) * C1);
  float w1 = bb.y * exp2f((bb.x - M) * C1);
  const float inv = 1.0f / (w0 + w1);
  w0 *= inv; w1 *= inv;
  bf16x8 v0 = *(const bf16x8*)(p0out + (size_t)i * 8);
  bf16x8 v1 = *(const bf16x8*)(p1 + (size_t)i * 8);
  ushort4 o0, o1;
  o0.x = f2bf(w0 * (float)v0[0] + w1 * (float)v1[0]);
  o0.y = f2bf(w0 * (float)v0[1] + w1 * (float)v1[1]);
  o0.z = f2bf(w0 * (float)v0[2] + w1 * (float)v1[2]);
  o0.w = f2bf(w0 * (float)v0[3] + w1 * (float)v1[3]);
  o1.x = f2bf(w0 * (float)v0[4] + w1 * (float)v1[4]);
  o1.y = f2bf(w0 * (float)v0[5] + w1 * (float)v1[5]);
  o1.z = f2bf(w0 * (float)v0[6] + w1 * (float)v1[6]);
  o1.w = f2bf(w0 * (float)v0[7] + w1 * (float)v1[7]);
  *(ushort4*)(p0out + (size_t)i * 8) = o0;
  *(ushort4*)(p0out + (size_t)i * 8 + 4) = o1;
}

// ---------------------------------------------------------------------------
extern "C" void kernel_launch(void* const* d_in, const int* in_sizes, int n_in,
                              void* d_out, int out_size, void* d_ws, size_t ws_size,
                              hipStream_t stream) {
  const float* x = (const float*)d_in[0];      // [4,4096,512] fp32
  const float* w_in = (const float*)d_in[1];   // [1536,512] fp32
  const float* b_in = (const float*)d_in[2];   // [1536] fp32
  const float* w_out = (const float*)d_in[3];  // [512,512] fp32
  const float* b_out = (const float*)d_in[4];  // [512] fp32
  float* out = (float*)d_out;                  // [4,4096,512] fp32

  const size_t MTOT = (size_t)4 * 4096 * 512;  // 8,388,608
  unsigned short* q = (unsigned short*)d_ws;
  unsigned short* k = q + MTOT;
  unsigned short* vt = k + MTOT;        // [b][d][s]
  unsigned short* xbf = vt + MTOT;      // x bf16 -> attn part0 -> merged ao
  unsigned short* part1 = xbf + MTOT;   // attn part1
  unsigned short* w_in_bf = part1 + MTOT;
  unsigned short* w_out_bf = w_in_bf + 1536 * 512;
  float2* mlbuf = (float2*)(w_out_bf + 512 * 512);  // 2 x 16384 float2

  cvt_f2bf<<<dim3((int)(MTOT / 4 / 256)), 256, 0, stream>>>(x, xbf,
                                                            (int)(MTOT / 4));
  cvt_f2bf<<<dim3(768), 256, 0, stream>>>(w_in, w_in_bf, 1536 * 512 / 4);
  cvt_f2bf<<<dim3(256), 256, 0, stream>>>(w_out, w_out_bf, 512 * 512 / 4);

  gemm_bt<<<dim3(12, 128), 256, 0, stream>>>(xbf, w_in_bf, b_in, nullptr, q, k,
                                             vt, 16384, 1536, 512, 1);
  // flash attention, kv-split-2 (part0 overwrites xbf; x is dead)
  attn_kernel<<<dim3(512), 256, 0, stream>>>(q, k, vt, xbf, part1, mlbuf);
  // merge halves in place into xbf
  merge_halves<<<dim3(4096), 256, 0, stream>>>(part1, mlbuf, xbf);
  // out = ao @ w_out^T + b_out  (fp32 output)
  gemm_bt<<<dim3(4, 128), 256, 0, stream>>>(xbf, w_out_bf, b_out, out, nullptr,
                                            nullptr, nullptr, 16384, 512, 512,
                                            0);
}

// Round 3
// 412.999 us; speedup vs baseline: 1.1049x; 1.1049x over previous
//
#include <hip/hip_runtime.h>

typedef __bf16 bf16x8 __attribute__((ext_vector_type(8)));
typedef float f32x4 __attribute__((ext_vector_type(4)));

#define MFMA16(a, b, c) __builtin_amdgcn_mfma_f32_16x16x32_bf16(a, b, c, 0, 0, 0)
#define LOG2E 1.44269504088896340736f

__device__ __forceinline__ unsigned short f2bf(float f) {
  union { float f; unsigned u; } v; v.f = f;
  return (unsigned short)((v.u + 0x7fffu + ((v.u >> 16) & 1u)) >> 16);
}
__device__ __forceinline__ bf16x8 ld_frag(const unsigned short* p) {
  return *(const bf16x8*)p;  // 16B-aligned by construction
}
__device__ __forceinline__ void gld_lds16(const unsigned short* g, unsigned short* l) {
  __builtin_amdgcn_global_load_lds(
      (const __attribute__((address_space(1))) unsigned int*)(const void*)g,
      (__attribute__((address_space(3))) unsigned int*)(void*)l, 16, 0, 0);
}

// fp32 -> bf16, 4 elements/thread
__global__ void cvt_f2bf(const float* __restrict__ in,
                         unsigned short* __restrict__ out, int n4) {
  int i = blockIdx.x * blockDim.x + threadIdx.x;
  if (i < n4) {
    float4 v = ((const float4*)in)[i];
    ushort4 o;
    o.x = f2bf(v.x); o.y = f2bf(v.y); o.z = f2bf(v.z); o.w = f2bf(v.w);
    ((ushort4*)out)[i] = o;
  }
}

// ---------------------------------------------------------------------------
// C[M,N] = A[M,K] * B[N,K]^T + bias[N]   (A,B bf16; bias fp32)
// mode 0: store fp32 to outf[M,N]
// mode 1: QKV split: n<512 -> qbuf; n<1024 -> kbuf; else transposed vtbuf[b][d][s]
// 128x128 tile, BK=32, 256 threads, 4 waves in 2x2, wave tile 64x64.
// ---------------------------------------------------------------------------
__global__ void gemm_bt(const unsigned short* __restrict__ A,
                        const unsigned short* __restrict__ B,
                        const float* __restrict__ bias,
                        float* __restrict__ outf,
                        unsigned short* __restrict__ qbuf,
                        unsigned short* __restrict__ kbuf,
                        unsigned short* __restrict__ vtbuf,
                        int M, int N, int K, int mode) {
  __shared__ alignas(16) unsigned short As[128 * 32];
  __shared__ alignas(16) unsigned short Bs[128 * 32];
  const int n0 = blockIdx.x * 128, m0 = blockIdx.y * 128;
  const int tid = threadIdx.x;
  const int l = tid & 63, w = tid >> 6;
  const int quad = l >> 4, c = l & 15;
  const int wm = (w >> 1) * 64, wn = (w & 1) * 64;

  f32x4 acc[4][4] = {};
  const int kiters = K >> 5;
  for (int kt = 0; kt < kiters; ++kt) {
    __syncthreads();
    const int kk = kt * 32 + (l & 3) * 8;
    const int row = l >> 2;
#pragma unroll
    for (int i = 0; i < 2; ++i) {
      const int rbase = i * 64 + w * 16;
      gld_lds16(&A[(size_t)(m0 + rbase + row) * K + kk], &As[rbase * 32]);
      gld_lds16(&B[(size_t)(n0 + rbase + row) * K + kk], &Bs[rbase * 32]);
    }
    __syncthreads();
    bf16x8 af[4], bfr[4];
#pragma unroll
    for (int t = 0; t < 4; ++t) {
      af[t] = ld_frag(&As[(wm + t * 16 + c) * 32 + quad * 8]);
      bfr[t] = ld_frag(&Bs[(wn + t * 16 + c) * 32 + quad * 8]);
    }
#pragma unroll
    for (int mt = 0; mt < 4; ++mt)
#pragma unroll
      for (int nt = 0; nt < 4; ++nt)
        acc[mt][nt] = MFMA16(af[mt], bfr[nt], acc[mt][nt]);
  }

#pragma unroll
  for (int nt = 0; nt < 4; ++nt) {
    const int n = n0 + wn + nt * 16 + c;
    const float bsum = bias[n];
#pragma unroll
    for (int mt = 0; mt < 4; ++mt) {
      const int mbase = m0 + wm + mt * 16 + quad * 4;
      if (mode == 0) {
#pragma unroll
        for (int r = 0; r < 4; ++r)
          outf[(size_t)(mbase + r) * N + n] = acc[mt][nt][r] + bsum;
      } else if (n < 1024) {
        unsigned short* dst = (n < 512) ? qbuf : kbuf;
        const int nn = n & 511;
#pragma unroll
        for (int r = 0; r < 4; ++r)
          dst[(size_t)(mbase + r) * 512 + nn] = f2bf(acc[mt][nt][r] + bsum);
      } else {
        const int d = n - 1024;
        const int bb = mbase >> 12, s = mbase & 4095;
        ushort4 pk;
        pk.x = f2bf(acc[mt][nt][0] + bsum);
        pk.y = f2bf(acc[mt][nt][1] + bsum);
        pk.z = f2bf(acc[mt][nt][2] + bsum);
        pk.w = f2bf(acc[mt][nt][3] + bsum);
        *(ushort4*)&vtbuf[((size_t)bb * 512 + d) * 4096 + s] = pk;
      }
    }
  }
}

// ---------------------------------------------------------------------------
// Flash attention, transposed-S, kv-split-2, d-split PV, software-pipelined:
// Grid 512 = 4b x 64qt x 2 kv-halves; block owns 64 q x 2048 kv (64 iters).
// Memory structure = round-1 (proven): K,V staged via global_load_lds, P via
// LDS (now double-buffered). Schedule pipelines QK one iteration ahead:
//   barB (vmcnt0+lgkm0: V(it) landed, P(it) published)
//   -> issue stage_k(it+1)            [flies over PV]
//   -> rescale + PV(it)
//   barC (lgkm0 only: V free)
//   -> issue stage_v(it+1)            [flies over QK+softmax]
//   -> vmcnt(8) = K(it+1) retired (in-order; leaves the 8 V loads in flight)
//   barA -> QK(it+1) + softmax(it+1) -> P[(it+1)&1]
// No barrier ever drains a just-issued stage. 3 raw s_barriers/iter.
// Regs: o = 8x4 f32x4 = 128 AGPR, VGPR ~128 -> 2 blocks/CU (8 waves).
// LDS: 33.3K (K) + 32K (V) + 10.2K (P dbuf) + misc = ~76KB -> 2 blocks/CU.
// ---------------------------------------------------------------------------
#define KROW 520
#define PROW 40
#define PBUF (64 * PROW)

__global__ __launch_bounds__(256, 2) void attn_kernel(
    const unsigned short* __restrict__ Q, const unsigned short* __restrict__ Kb,
    const unsigned short* __restrict__ Vt, unsigned short* __restrict__ part0,
    unsigned short* __restrict__ part1, float2* __restrict__ mlbuf) {
  __shared__ alignas(16) unsigned short k_lds[32 * KROW];
  __shared__ alignas(16) unsigned short v_lds[512 * 32];
  __shared__ alignas(16) unsigned short p_lds[2 * PBUF];
  __shared__ float alpha_s[64];  // per-q rescale factor (and l at epilogue)
  __shared__ int flag_s[4];      // per-softmax-wave rescale flag

  const int bid = blockIdx.x;
  const int xcd = bid & 7;
  const int b = xcd >> 1;                          // 2 XCDs per batch
  const int half = (bid >> 3) & 1;                 // kv half
  const int qt = (bid >> 4) | ((xcd & 1) << 5);    // 0..63
  const int s0 = qt * 64;
  const int kvbase = half * 2048;
  const int tid = threadIdx.x;
  const int l = tid & 63, w = tid >> 6;
  const int quad = l >> 4, c = l & 15;
  const size_t boff = (size_t)b * 4096 * 512;

  const unsigned short* Kbase = Kb + boff;
  const unsigned short* Vbase = Vt + (size_t)b * 512 * 4096;

  auto stage_k = [&](int kv0) {
#pragma unroll
    for (int i = 0; i < 8; ++i) {  // K: one 1KB row per wave per call
      const int row = i * 4 + w;
      gld_lds16(&Kbase[(size_t)(kv0 + row) * 512 + l * 8], &k_lds[row * KROW]);
    }
  };
  auto stage_v = [&](int kv0) {
#pragma unroll
    for (int i = 0; i < 8; ++i) {  // Vt: XOR-swizzled kv-chunks
      const int dbase = (i * 4 + w) * 16;
      const int d = dbase + (l >> 2);
      const int jl = (l & 3) ^ ((d >> 1) & 3);
      gld_lds16(&Vbase[(size_t)d * 4096 + kv0 + jl * 8], &v_lds[dbase * 32]);
    }
  };

  stage_k(kvbase);
  stage_v(kvbase);

  // Q fragments pinned (A/B-operand layout: idx = c, k = quad*8+j)
  bf16x8 qf[16];
  {
    const unsigned short* qrow = Q + boff + (size_t)(s0 + w * 16 + c) * 512;
#pragma unroll
    for (int ks = 0; ks < 16; ++ks) qf[ks] = ld_frag(&qrow[ks * 32 + quad * 8]);
  }

  // O^T, d-split: o[t][j] holds [d = w*128 + t*16 + quad*4 + r][q = j*16 + c]
  f32x4 o[8][4] = {};
  float m_run = -1e30f, l_run = 0.f;  // per-lane (q = w*16+c), repl. over quads

  const float C1 = 0.125f * LOG2E;

  // QK^T + online softmax for this wave's 16 q; writes P[(i&1)], alpha, flag.
  auto qk_softmax = [&](int i) {
    f32x4 sa[2][2] = {};
    __builtin_amdgcn_s_setprio(1);
#pragma unroll
    for (int ks = 0; ks < 16; ++ks) {
      const unsigned short* kr = &k_lds[c * KROW + ks * 32 + quad * 8];
      bf16x8 kf0 = ld_frag(kr);
      bf16x8 kf1 = ld_frag(kr + 16 * KROW);
      sa[0][ks & 1] = MFMA16(kf0, qf[ks], sa[0][ks & 1]);
      sa[1][ks & 1] = MFMA16(kf1, qf[ks], sa[1][ks & 1]);
    }
    __builtin_amdgcn_s_setprio(0);
    const f32x4 s0v = sa[0][0] + sa[0][1];  // kv = quad*4+r, q = w*16+c
    const f32x4 s1v = sa[1][0] + sa[1][1];  // kv = 16+quad*4+r

    float m8 = fmaxf(fmaxf(fmaxf(s0v[0], s0v[1]), fmaxf(s0v[2], s0v[3])),
                     fmaxf(fmaxf(s1v[0], s1v[1]), fmaxf(s1v[2], s1v[3])));
    m8 = fmaxf(m8, __shfl_xor(m8, 16));
    m8 = fmaxf(m8, __shfl_xor(m8, 32));

    // defer-max (T13): only rescale when the tile max grows > 8 raw units
    // (exp2 arg bounded by 8*C1 = 1.44 -> P <= 2.72, safe in fp32 accum)
    const bool need = __any(m8 - m_run > 8.0f);
    float alpha = 1.0f;
    if (need) {
      const float mn = fmaxf(m_run, m8);
      alpha = exp2f((m_run - mn) * C1);
      m_run = mn;
      l_run *= alpha;
    }

    float p0[4], p1[4], s8 = 0.f;
#pragma unroll
    for (int r = 0; r < 4; ++r) {
      p0[r] = exp2f((s0v[r] - m_run) * C1);
      p1[r] = exp2f((s1v[r] - m_run) * C1);
      s8 += p0[r] + p1[r];
    }
    // store P^T rows [q][kv] (two ushort4 = 2x ds_write_b64)
    unsigned short* prow = &p_lds[(i & 1) * PBUF + (w * 16 + c) * PROW];
    ushort4 pk0, pk1;
    pk0.x = f2bf(p0[0]); pk0.y = f2bf(p0[1]); pk0.z = f2bf(p0[2]); pk0.w = f2bf(p0[3]);
    pk1.x = f2bf(p1[0]); pk1.y = f2bf(p1[1]); pk1.z = f2bf(p1[2]); pk1.w = f2bf(p1[3]);
    *(ushort4*)&prow[quad * 4] = pk0;
    *(ushort4*)&prow[16 + quad * 4] = pk1;

    s8 += __shfl_xor(s8, 16);
    s8 += __shfl_xor(s8, 32);
    l_run += s8;

    if (quad == 0) alpha_s[w * 16 + c] = alpha;
    if (l == 0) flag_s[w] = need ? 1 : 0;
  };

  const int jp8 = (quad ^ ((c >> 1) & 3)) * 8;  // t-independent V read swizzle

  // prologue: K(0),V(0) landed; compute QK(0)+softmax(0) -> P buffer 0
  asm volatile("s_waitcnt vmcnt(0)" ::: "memory");
  __builtin_amdgcn_sched_barrier(0);
  __builtin_amdgcn_s_barrier();
  __builtin_amdgcn_sched_barrier(0);
  qk_softmax(0);

  for (int it = 0; it < 64; ++it) {
    // --- barB: V(it) landed (own vmcnt), P(it)/alpha/flag committed (lgkm)
    asm volatile("s_waitcnt vmcnt(0) lgkmcnt(0)" ::: "memory");
    __builtin_amdgcn_sched_barrier(0);
    __builtin_amdgcn_s_barrier();
    __builtin_amdgcn_sched_barrier(0);

    if (it + 1 < 64) stage_k(kvbase + (it + 1) * 32);  // K(it) free; flies over PV

    // per-q-group rescale of the d-split accumulator (uniform branch per group)
    const int f0 = flag_s[0], f1 = flag_s[1], f2 = flag_s[2], f3 = flag_s[3];
    if (f0) {
      const float a = alpha_s[c];
#pragma unroll
      for (int t = 0; t < 8; ++t) o[t][0] *= a;
    }
    if (f1) {
      const float a = alpha_s[16 + c];
#pragma unroll
      for (int t = 0; t < 8; ++t) o[t][1] *= a;
    }
    if (f2) {
      const float a = alpha_s[32 + c];
#pragma unroll
      for (int t = 0; t < 8; ++t) o[t][2] *= a;
    }
    if (f3) {
      const float a = alpha_s[48 + c];
#pragma unroll
      for (int t = 0; t < 8; ++t) o[t][3] *= a;
    }

    // --- O^T += V^T P^T, d-split: A = V frag (reused over 4 q-tiles),
    // B = P frag (reused over 8 d-tiles); 12 ds_read_b128 per 32 MFMA.
    const unsigned short* pb = &p_lds[(it & 1) * PBUF];
    const bf16x8 pf0 = ld_frag(&pb[(size_t)c * PROW + quad * 8]);
    const bf16x8 pf1 = ld_frag(&pb[(size_t)(16 + c) * PROW + quad * 8]);
    const bf16x8 pf2 = ld_frag(&pb[(size_t)(32 + c) * PROW + quad * 8]);
    const bf16x8 pf3 = ld_frag(&pb[(size_t)(48 + c) * PROW + quad * 8]);
    __builtin_amdgcn_s_setprio(1);
#pragma unroll
    for (int t = 0; t < 8; ++t) {
      const bf16x8 vf = ld_frag(&v_lds[(w * 128 + t * 16 + c) * 32 + jp8]);
      o[t][0] = MFMA16(vf, pf0, o[t][0]);
      o[t][1] = MFMA16(vf, pf1, o[t][1]);
      o[t][2] = MFMA16(vf, pf2, o[t][2]);
      o[t][3] = MFMA16(vf, pf3, o[t][3]);
    }
    __builtin_amdgcn_s_setprio(0);

    // --- barC: own PV LDS reads done -> V buffer free block-wide
    asm volatile("s_waitcnt lgkmcnt(0)" ::: "memory");
    __builtin_amdgcn_sched_barrier(0);
    __builtin_amdgcn_s_barrier();
    __builtin_amdgcn_sched_barrier(0);

    if (it + 1 < 64) {
      stage_v(kvbase + (it + 1) * 32);  // flies over QK+softmax
      // K(it+1) retired: vmcnt in-order; 8 V loads just issued stay in flight
      asm volatile("s_waitcnt vmcnt(8)" ::: "memory");
      __builtin_amdgcn_sched_barrier(0);
      __builtin_amdgcn_s_barrier();  // barA: K(it+1) visible to all waves
      __builtin_amdgcn_sched_barrier(0);
      qk_softmax(it + 1);
    }
  }

  // epilogue: exchange l across waves (softmax q-split -> O d-split), then
  // write normalized partial + (m,l) for the merge
  if (quad == 0) {
    alpha_s[w * 16 + c] = l_run;
    float2 ml; ml.x = m_run; ml.y = l_run;
    mlbuf[(size_t)half * 16384 + b * 4096 + s0 + w * 16 + c] = ml;
  }
  __syncthreads();
  const float linv0 = 1.0f / alpha_s[c];
  const float linv1 = 1.0f / alpha_s[16 + c];
  const float linv2 = 1.0f / alpha_s[32 + c];
  const float linv3 = 1.0f / alpha_s[48 + c];

  unsigned short* part = half ? part1 : part0;
  unsigned short* obase = part + boff + (size_t)s0 * 512 + w * 128 + quad * 4;
#pragma unroll
  for (int t = 0; t < 8; ++t) {
    const float li[4] = {linv0, linv1, linv2, linv3};
#pragma unroll
    for (int j = 0; j < 4; ++j) {
      ushort4 pk;
      pk.x = f2bf(o[t][j][0] * li[j]);
      pk.y = f2bf(o[t][j][1] * li[j]);
      pk.z = f2bf(o[t][j][2] * li[j]);
      pk.w = f2bf(o[t][j][3] * li[j]);
      *(ushort4*)&obase[(size_t)(j * 16 + c) * 512 + t * 16] = pk;
    }
  }
}

// ---------------------------------------------------------------------------
// Merge the two kv-half streams: out = (w0*P0 + w1*P1), w_h = l_h*2^((m_h-M)*C1)
// 8 elems/thread; writes in place over part0.
// ---------------------------------------------------------------------------
__global__ void merge_halves(const unsigned short* __restrict__ p1,
                             const float2* __restrict__ mlbuf,
                             unsigned short* __restrict__ p0out) {
  const int i = blockIdx.x * blockDim.x + threadIdx.x;  // one per 8 elems
  const int row = i >> 6;                               // 512 d / 8 = 64
  const float2 a = mlbuf[row];
  const float2 bb = mlbuf[16384 + row];
  const float C1 = 0.125f * LOG2E;
  const float M = fmaxf(a.x, bb.x);
  float w0 = a.y * exp2f((a.x - M) * C1);
  float w1 = bb.y * exp2f((bb.x - M) * C1);
  const float inv = 1.0f / (w0 + w1);
  w0 *= inv; w1 *= inv;
  bf16x8 v0 = *(const bf16x8*)(p0out + (size_t)i * 8);
  bf16x8 v1 = *(const bf16x8*)(p1 + (size_t)i * 8);
  ushort4 o0, o1;
  o0.x = f2bf(w0 * (float)v0[0] + w1 * (float)v1[0]);
  o0.y = f2bf(w0 * (float)v0[1] + w1 * (float)v1[1]);
  o0.z = f2bf(w0 * (float)v0[2] + w1 * (float)v1[2]);
  o0.w = f2bf(w0 * (float)v0[3] + w1 * (float)v1[3]);
  o1.x = f2bf(w0 * (float)v0[4] + w1 * (float)v1[4]);
  o1.y = f2bf(w0 * (float)v0[5] + w1 * (float)v1[5]);
  o1.z = f2bf(w0 * (float)v0[6] + w1 * (float)v1[6]);
  o1.w = f2bf(w0 * (float)v0[7] + w1 * (float)v1[7]);
  *(ushort4*)(p0out + (size_t)i * 8) = o0;
  *(ushort4*)(p0out + (size_t)i * 8 + 4) = o1;
}

// ---------------------------------------------------------------------------
extern "C" void kernel_launch(void* const* d_in, const int* in_sizes, int n_in,
                              void* d_out, int out_size, void* d_ws, size_t ws_size,
                              hipStream_t stream) {
  const float* x = (const float*)d_in[0];      // [4,4096,512] fp32
  const float* w_in = (const float*)d_in[1];   // [1536,512] fp32
  const float* b_in = (const float*)d_in[2];   // [1536] fp32
  const float* w_out = (const float*)d_in[3];  // [512,512] fp32
  const float* b_out = (const float*)d_in[4];  // [512] fp32
  float* out = (float*)d_out;                  // [4,4096,512] fp32

  const size_t MTOT = (size_t)4 * 4096 * 512;  // 8,388,608
  unsigned short* q = (unsigned short*)d_ws;
  unsigned short* k = q + MTOT;
  unsigned short* vt = k + MTOT;        // [b][d][s]
  unsigned short* xbf = vt + MTOT;      // x bf16 -> attn part0 -> merged ao
  unsigned short* part1 = xbf + MTOT;   // attn part1
  unsigned short* w_in_bf = part1 + MTOT;
  unsigned short* w_out_bf = w_in_bf + 1536 * 512;
  float2* mlbuf = (float2*)(w_out_bf + 512 * 512);  // 2 x 16384 float2

  cvt_f2bf<<<dim3((int)(MTOT / 4 / 256)), 256, 0, stream>>>(x, xbf,
                                                            (int)(MTOT / 4));
  cvt_f2bf<<<dim3(768), 256, 0, stream>>>(w_in, w_in_bf, 1536 * 512 / 4);
  cvt_f2bf<<<dim3(256), 256, 0, stream>>>(w_out, w_out_bf, 512 * 512 / 4);

  gemm_bt<<<dim3(12, 128), 256, 0, stream>>>(xbf, w_in_bf, b_in, nullptr, q, k,
                                             vt, 16384, 1536, 512, 1);
  // flash attention, kv-split-2 (part0 overwrites xbf; x is dead)
  attn_kernel<<<dim3(512), 256, 0, stream>>>(q, k, vt, xbf, part1, mlbuf);
  // merge halves in place into xbf
  merge_halves<<<dim3(4096), 256, 0, stream>>>(part1, mlbuf, xbf);
  // out = ao @ w_out^T + b_out  (fp32 output)
  gemm_bt<<<dim3(4, 128), 256, 0, stream>>>(xbf, w_out_bf, b_out, out, nullptr,
                                            nullptr, nullptr, 16384, 512, 512,
                                            0);
}